// Round 9
// baseline (533.473 us; speedup 1.0000x reference)
//
#include <hip/hip_runtime.h>
#include <stdint.h>

#define BB 16384
#define ZZ 64
#define DD 66
#define NB 4          // batch rows per wave
#define WPB 4         // waves per block
#define ROWS (WPB*NB) // 16 rows per block
#define CH  6         // d's per LDS weight chunk (66 = 6*11)
#define NCH 11
#define WCH (CH*4*64*4)   // 6144 floats of W1T per chunk
#define SCH (CH*ZZ*2)     // 768 floats of svmu per chunk
#define CHF (WCH+SCH)     // 6912 floats per LDS buffer (27 KB)

// ---- ws float offsets (filled by prep kernel every launch) ----
#define OFF_SVMU 0            // [66][64] float2 (mult_u, sqrt(var_u)) -> 8448 floats
#define OFF_C0U  8448
#define OFF_MG   8512
#define OFF_SVG  8576
#define OFF_C0G  8640
#define OFF_W1T  8704         // [66][4][64][4] floats = 67584 (coalesced W1)
#define OFF_W2T  76288        // [16][4][64][4] floats = 16384 (coalesced W2)
#define OFF_W3T  92672        // [8][64][4]    floats = 2048  (coalesced W3)

// Fold exps/constants + transpose weights into lane-coalesced layouts.
__global__ void prep_kernel(const float* __restrict__ mult_u, const float* __restrict__ logvar_u,
                            const float* __restrict__ mult_g, const float* __restrict__ logvar_g,
                            const float* __restrict__ W1, const float* __restrict__ W2,
                            const float* __restrict__ W3, float* __restrict__ ws) {
  const int d = blockIdx.x;   // 0..65
  const int t = threadIdx.x;
  const int z = t >> 2, q = t & 3;

  {
    const float4 v = *reinterpret_cast<const float4*>(W1 + (z*DD + d)*16 + q*4);
    *reinterpret_cast<float4*>(ws + OFF_W1T + ((d*4 + q)*64 + z)*4) = v;
  }
  if (t < ZZ) {
    ws[OFF_SVMU + 2*(d*ZZ + t)]     = mult_u[d*ZZ + t];
    ws[OFF_SVMU + 2*(d*ZZ + t) + 1] = __expf(0.5f * logvar_u[d*ZZ + t]);
  }
  if (d < 16) {
    const float4 v = *reinterpret_cast<const float4*>(W2 + (z*16 + d)*16 + q*4);
    *reinterpret_cast<float4*>(ws + OFF_W2T + ((d*4 + q)*64 + z)*4) = v;
  }
  if (d == 16 || d == 17) {
    const int idx = (d - 16)*256 + t;
    const int qq = idx >> 6, zz = idx & 63;
    const float4 v = *reinterpret_cast<const float4*>(W3 + zz*32 + qq*4);
    *reinterpret_cast<float4*>(ws + OFF_W3T + (qq*64 + zz)*4) = v;
  }
  if (d == 0) {
    if (t < ZZ) {
      float s = 0.f;
      for (int dd = 0; dd < DD; ++dd) {
        const float lv = logvar_u[dd*ZZ + t];
        s += 1.f + lv - __expf(lv);
      }
      ws[OFF_C0U + t] = -0.5f * s;
      ws[OFF_MG  + t] = mult_g[t];
      ws[OFF_SVG + t] = __expf(0.5f * logvar_g[t]);
    }
    if (t == 0) {
      float s = 0.f;
      for (int zc = 0; zc < ZZ; ++zc) {
        const float lv = logvar_g[zc];
        s += 1.f + lv - __expf(lv);
      }
      ws[OFF_C0G] = -0.5f * s;
    }
  }
}

// Main: lane = z; wave handles NB batch rows.
// r8 post-mortem: noise MLP was NOT the bottleneck (chunk staging = no change).
// The serial cost is the PER-WAVE weight stream from L2 (264 dwordx4/wave at
// ~200-400cy each, only 2 waves/SIMD to hide it). Fix: stage W1T+svmu chunks
// into an LDS double buffer ONCE PER BLOCK (all 4 waves share), one barrier
// per 6-d chunk. Per-iter weight access becomes ds_read_b128 (~85 B/cy/CU).
// Noise: r7's proven scalar depth-2 register prefetch.
// launch_bounds(256,1): (256,2) clamps VGPR->128 and spills ~170 MB (r2 PMC).
__global__ __launch_bounds__(256, 1)
void disrnn_main(const float* __restrict__ latents, const float* __restrict__ obs,
                 const float* __restrict__ noise_u, const float* __restrict__ noise_g,
                 const float* __restrict__ z0, const float* __restrict__ b1,
                 const float* __restrict__ b2, const float* __restrict__ b3,
                 const float* __restrict__ Wc1, const float* __restrict__ bc1,
                 const float* __restrict__ Wc2, const float* __restrict__ bc2,
                 const float* __restrict__ Wc3, const float* __restrict__ bc3,
                 const float* __restrict__ ws, const int* __restrict__ t0p,
                 float* __restrict__ out) {
  float* out_zt = out + BB*2;
  float* out_kg = out + BB*2 + BB*ZZ;
  float* out_ku = out + BB*2 + BB*ZZ + BB;

  __shared__ float x_lds[WPB][NB][68];
  __shared__ float wlds[2][CHF];      // 54 KB: block-shared weight double buffer
  __shared__ float ztl[ROWS][64];
  __shared__ float y1[ROWS][32];
  __shared__ float y2[ROWS][32];

  const int tid  = threadIdx.x;
  const int w    = tid >> 6;
  const int lane = tid & 63;
  const int b0   = (blockIdx.x * WPB + w) * NB;
  const int t0   = *t0p;

#pragma unroll
  for (int i = 0; i < NB; ++i) {
    x_lds[w][i][lane] = t0 ? z0[lane] : latents[(b0 + i)*ZZ + lane];
    if (lane < 2) x_lds[w][i][ZZ + lane] = obs[(b0 + i)*2 + lane];
  }

  const float* w1t = ws + OFF_W1T;
  const float* svm = ws + OFF_SVMU;

  // stage chunk 0 into buffer 0 (cooperative, 1728 float4s / 256 threads)
  {
    const float4* sw = reinterpret_cast<const float4*>(w1t);
    const float4* sv = reinterpret_cast<const float4*>(svm);
    float4* dst = reinterpret_cast<float4*>(wlds[0]);
    for (int t = tid; t < CHF/4; t += 256) {
      const float4* src = (t < WCH/4) ? (sw + t) : (sv + (t - WCH/4));
      dst[t] = *src;
    }
  }
  __syncthreads();   // covers x_lds too

  const float c0u_l = ws[OFF_C0U + lane];
  const float mg_l  = ws[OFF_MG + lane];
  const float svg_l = ws[OFF_SVG + lane];
  const float c0g   = ws[OFF_C0G];

  float acc[NB][16], kacc[NB];
  {
    const float4* bp = reinterpret_cast<const float4*>(b1 + lane*16);
    float b1r[16];
#pragma unroll
    for (int q = 0; q < 4; ++q) {
      const float4 v = bp[q];
      b1r[4*q] = v.x; b1r[4*q+1] = v.y; b1r[4*q+2] = v.z; b1r[4*q+3] = v.w;
    }
#pragma unroll
    for (int i = 0; i < NB; ++i) {
      kacc[i] = 0.f;
#pragma unroll
      for (int h = 0; h < 16; ++h) acc[i][h] = b1r[h];
    }
  }

  const float* np[NB];
#pragma unroll
  for (int i = 0; i < NB; ++i) np[i] = noise_u + (size_t)(b0 + i)*DD*ZZ + lane;

  // noise register pipeline prologue (depth-2, proven adequate in r7/r8)
  float nv_c[NB], nv_n[NB];
#pragma unroll
  for (int i = 0; i < NB; ++i) { nv_c[i] = np[i][0]; nv_n[i] = np[i][ZZ]; }

  int d = 0;
  for (int c = 0; c < NCH; ++c) {
    const float* wb = wlds[c & 1];
    // issue next chunk's staging (targets the other buffer; latency hides
    // under this chunk's 6 iterations of compute)
    if (c + 1 < NCH) {
      const float4* sw = reinterpret_cast<const float4*>(w1t + (size_t)(c+1)*WCH);
      const float4* sv = reinterpret_cast<const float4*>(svm + (size_t)(c+1)*SCH);
      float4* dst = reinterpret_cast<float4*>(wlds[(c+1) & 1]);
      for (int t = tid; t < CHF/4; t += 256) {
        const float4* src = (t < WCH/4) ? (sw + t) : (sv + (t - WCH/4));
        dst[t] = *src;
      }
    }
    // load dc=0 weights/x from LDS (exposed ~120cy once per chunk)
    float wv_c[16];
#pragma unroll
    for (int q = 0; q < 4; ++q) {
      const float4 v = *reinterpret_cast<const float4*>(wb + (q*64 + lane)*4);
      wv_c[4*q] = v.x; wv_c[4*q+1] = v.y; wv_c[4*q+2] = v.z; wv_c[4*q+3] = v.w;
    }
    float2 sm_c = *reinterpret_cast<const float2*>(wb + WCH + lane*2);
    float xv_c[NB];
#pragma unroll
    for (int i = 0; i < NB; ++i) xv_c[i] = x_lds[w][i][d];

#pragma unroll
    for (int dc = 0; dc < CH; ++dc, ++d) {
      // noise depth-2 prefetch
      const int dnn = (d + 2 < DD) ? d + 2 : DD - 1;
      float nv2[NB];
#pragma unroll
      for (int i = 0; i < NB; ++i) nv2[i] = np[i][dnn*ZZ];
      // weight/x depth-1 prefetch from LDS (clamped at chunk end; dead value)
      const int dcn = (dc + 1 < CH) ? dc + 1 : dc;
      const int dn  = (d + 1 < DD) ? d + 1 : d;
      float wv_n[16];
#pragma unroll
      for (int q = 0; q < 4; ++q) {
        const float4 v = *reinterpret_cast<const float4*>(wb + ((dcn*4 + q)*64 + lane)*4);
        wv_n[4*q] = v.x; wv_n[4*q+1] = v.y; wv_n[4*q+2] = v.z; wv_n[4*q+3] = v.w;
      }
      const float2 sm_n = *reinterpret_cast<const float2*>(wb + WCH + dcn*128 + lane*2);
      float xv_n[NB];
#pragma unroll
      for (int i = 0; i < NB; ++i) xv_n[i] = x_lds[w][i][dn];

      // compute iteration d
#pragma unroll
      for (int i = 0; i < NB; ++i) {
        const float mean = xv_c[i] * sm_c.x;
        kacc[i] = fmaf(mean, mean, kacc[i]);
        const float xt = fmaf(nv_c[i], sm_c.y, mean);
#pragma unroll
        for (int h = 0; h < 16; ++h) acc[i][h] = fmaf(xt, wv_c[h], acc[i][h]);
      }
      // rotate
#pragma unroll
      for (int i = 0; i < NB; ++i) { nv_c[i] = nv_n[i]; nv_n[i] = nv2[i]; xv_c[i] = xv_n[i]; }
#pragma unroll
      for (int h = 0; h < 16; ++h) wv_c[h] = wv_n[h];
      sm_c = sm_n;
    }
    // barrier: (a) staging of buf^1 complete+visible, (b) all waves done
    // reading buf before it is overwritten next-next chunk
    __syncthreads();
  }

  // ---- layer 2 (coalesced W2T from global/L2, once per wave) ----
  float h2[NB][16];
  {
    const float4* bp = reinterpret_cast<const float4*>(b2 + lane*16);
    float b2r[16];
#pragma unroll
    for (int q = 0; q < 4; ++q) {
      const float4 v = bp[q];
      b2r[4*q] = v.x; b2r[4*q+1] = v.y; b2r[4*q+2] = v.z; b2r[4*q+3] = v.w;
    }
#pragma unroll
    for (int i = 0; i < NB; ++i) {
#pragma unroll
      for (int h = 0; h < 16; ++h) acc[i][h] = fmaxf(acc[i][h], 0.f);
#pragma unroll
      for (int k = 0; k < 16; ++k) h2[i][k] = b2r[k];
    }
  }
  const float* w2t = ws + OFF_W2T;
#pragma unroll
  for (int h = 0; h < 16; ++h) {
    float wv2[16];
#pragma unroll
    for (int q = 0; q < 4; ++q) {
      const float4 v = *reinterpret_cast<const float4*>(w2t + ((h*4 + q)*64 + lane)*4);
      wv2[4*q] = v.x; wv2[4*q+1] = v.y; wv2[4*q+2] = v.z; wv2[4*q+3] = v.w;
    }
#pragma unroll
    for (int i = 0; i < NB; ++i) {
      const float hv = acc[i][h];
#pragma unroll
      for (int k = 0; k < 16; ++k) h2[i][k] = fmaf(hv, wv2[k], h2[i][k]);
    }
  }

  // ---- layer 3 + gate + kld/z_tilde outputs (coalesced W3T) ----
  float w3r[32];
  {
    const float* w3t = ws + OFF_W3T;
#pragma unroll
    for (int q = 0; q < 8; ++q) {
      const float4 v = *reinterpret_cast<const float4*>(w3t + (q*64 + lane)*4);
      w3r[4*q] = v.x; w3r[4*q+1] = v.y; w3r[4*q+2] = v.z; w3r[4*q+3] = v.w;
    }
  }
  const float2 b3v = reinterpret_cast<const float2*>(b3)[lane];
#pragma unroll
  for (int i = 0; i < NB; ++i) {
    const int b = b0 + i;
    float o0 = b3v.x, o1 = b3v.y;
#pragma unroll
    for (int k = 0; k < 16; ++k) {
      const float hv = fmaxf(h2[i][k], 0.f);
      o0 = fmaf(hv, w3r[2*k], o0);
      o1 = fmaf(hv, w3r[2*k + 1], o1);
    }
    const float xl = x_lds[w][i][lane];
    const float wg = 1.f / (1.f + __expf(-o1));
    const float nl = fmaf(wg, o0 - xl, xl);        // (1-w)*lat + u*w
    const float tg = mg_l * nl;
    const float zt = fmaf(noise_g[b*ZZ + lane], svg_l, tg);
    out_zt[b*ZZ + lane] = zt;
    out_ku[b*ZZ + lane] = fmaf(0.5f, kacc[i], c0u_l);
    ztl[w*NB + i][lane] = zt;
    float t2 = tg * tg;
#pragma unroll
    for (int off = 32; off; off >>= 1) t2 += __shfl_xor(t2, off);
    if (lane == 0) out_kg[b] = fmaf(0.5f, t2, c0g);
  }
  __syncthreads();

  // ---- fused choice MLP: 16 rows x 32 neurons, 256 threads -> 2 row-groups ----
  const int r  = tid >> 5;
  const int hc = tid & 31;
#pragma unroll
  for (int g = 0; g < 2; ++g) {
    const int row = g*8 + r;
    float a = bc1[hc];
#pragma unroll
    for (int zc = 0; zc < 64; ++zc) a = fmaf(ztl[row][zc], Wc1[zc*32 + hc], a);
    y1[row][hc] = fmaxf(a, 0.f);
  }
  __syncthreads();
#pragma unroll
  for (int g = 0; g < 2; ++g) {
    const int row = g*8 + r;
    float a = bc2[hc];
#pragma unroll
    for (int k = 0; k < 32; ++k) a = fmaf(y1[row][k], Wc2[k*32 + hc], a);
    y2[row][hc] = fmaxf(a, 0.f);
  }
  __syncthreads();
  if (tid < ROWS*2) {
    const int rr = tid >> 1, o = tid & 1;
    float s = bc3[o];
#pragma unroll
    for (int k = 0; k < 32; ++k) s = fmaf(y2[rr][k], Wc3[2*k + o], s);
    out[(blockIdx.x*ROWS + rr)*2 + o] = s;
  }
}

extern "C" void kernel_launch(void* const* d_in, const int* in_sizes, int n_in,
                              void* d_out, int out_size, void* d_ws, size_t ws_size,
                              hipStream_t stream) {
  (void)in_sizes; (void)n_in; (void)out_size; (void)ws_size;
  const float* latents  = (const float*)d_in[0];
  const float* obs      = (const float*)d_in[1];
  const float* noise_u  = (const float*)d_in[2];
  const float* noise_g  = (const float*)d_in[3];
  const float* z0       = (const float*)d_in[4];
  const float* mult_u   = (const float*)d_in[5];
  const float* logvar_u = (const float*)d_in[6];
  const float* mult_g   = (const float*)d_in[7];
  const float* logvar_g = (const float*)d_in[8];
  const float* W1       = (const float*)d_in[9];
  const float* b1       = (const float*)d_in[10];
  const float* W2       = (const float*)d_in[11];
  const float* b2       = (const float*)d_in[12];
  const float* W3       = (const float*)d_in[13];
  const float* b3       = (const float*)d_in[14];
  const float* Wc1      = (const float*)d_in[15];
  const float* bc1      = (const float*)d_in[16];
  const float* Wc2      = (const float*)d_in[17];
  const float* bc2      = (const float*)d_in[18];
  const float* Wc3      = (const float*)d_in[19];
  const float* bc3      = (const float*)d_in[20];
  const int*  t0p       = (const int*)d_in[21];
  float* ws   = (float*)d_ws;
  float* outp = (float*)d_out;

  prep_kernel<<<66, 256, 0, stream>>>(mult_u, logvar_u, mult_g, logvar_g, W1, W2, W3, ws);
  disrnn_main<<<BB/ROWS, 256, 0, stream>>>(latents, obs, noise_u, noise_g, z0,
                                           b1, b2, b3, Wc1, bc1, Wc2, bc2, Wc3, bc3,
                                           ws, t0p, outp);
}